// Round 10
// baseline (38.829 us; speedup 1.0000x reference)
//
#include <hip/hip_runtime.h>
#include <hip/hip_bf16.h>

#define D_IN  512
#define C_OUT 128
#define HW    16384   // 128*128 per batch
#define BM    128
#define BK    64
#define PAD   72      // 144B row stride -> 2-way LDS aliasing on b128 reads (free, m136)
#define NKT   (D_IN / BK)   // 8 K-steps

typedef __attribute__((ext_vector_type(8))) short bf16x8;
typedef __attribute__((ext_vector_type(4))) float f32x4;

__device__ __forceinline__ ushort bfc(float f) {
    // scalar cast -> compiler emits packed v_cvt_pk_bf16_f32 (RNE), per m240
    return __builtin_bit_cast(ushort, __float2bfloat16(f));
}

__device__ __forceinline__ bf16x8 pack8(f32x4 a, f32x4 b) {
    bf16x8 r;
    r[0] = (short)bfc(a[0]); r[1] = (short)bfc(a[1]);
    r[2] = (short)bfc(a[2]); r[3] = (short)bfc(a[3]);
    r[4] = (short)bfc(b[0]); r[5] = (short)bfc(b[1]);
    r[6] = (short)bfc(b[2]); r[7] = (short)bfc(b[3]);
    return r;
}

__global__ __launch_bounds__(256, 2) void cwp_gemm(
    const float* __restrict__ x, const float* __restrict__ W,
    const float* __restrict__ bias, float* __restrict__ out)
{
    // W only in LDS, double-buffered: 2 x 128 x 72 x 2B = 36 KB -> 2 blocks/CU
    __shared__ ushort Ws[2][C_OUT * PAD];

    const int t    = threadIdx.x;
    const int lane = t & 63;
    const int wid  = t >> 6;     // 0..3 : wave owns 32 m-rows x ALL 128 channels
    const int q    = lane >> 4;  // 0..3
    const int lr   = lane & 15;

    const int m0   = blockIdx.x * BM;
    const int bidx = m0 / HW;
    const int hw0  = m0 % HW;

    const int srow = t >> 4;     // 0..15 W-staging row base
    const int scol = t & 15;     // f32x4 column within BK

    // x lane pointers in B-fragment order: row (l&15), k-chunk (l>>4)*8.
    // The +0/+4 load pair tiles a 128B-aligned span -> full-line coverage.
    const float* xp0 = x + (size_t)(m0 + wid * 32 + lr) * D_IN + q * 8;      // mt=0
    const float* xp1 = xp0 + 16 * D_IN;                                       // mt=1

    f32x4 acc[8][2];   // [ci: 16-channel tile][mt: 16-row tile]
    #pragma unroll
    for (int ci = 0; ci < 8; ++ci)
        #pragma unroll
        for (int mt = 0; mt < 2; ++mt)
            acc[ci][mt] = (f32x4){0.f, 0.f, 0.f, 0.f};

    // xr[mt*4 + ks*2 + h] <- x[row mt][kt + ks*32 + q*8 + h*4 ..+4)
    f32x4 xr[8], wr_[8];

    // ---- prologue: x(0) + W(0) ----
    #pragma unroll
    for (int ks = 0; ks < 2; ++ks)
        #pragma unroll
        for (int h = 0; h < 2; ++h) {
            xr[0*4 + ks*2 + h] = *reinterpret_cast<const f32x4*>(xp0 + ks*32 + h*4);
            xr[1*4 + ks*2 + h] = *reinterpret_cast<const f32x4*>(xp1 + ks*32 + h*4);
        }
    #pragma unroll
    for (int p = 0; p < 8; ++p) {
        const int r = p * 16 + srow;
        wr_[p] = *reinterpret_cast<const f32x4*>(&W[r * D_IN + scol * 4]);
    }
    #pragma unroll
    for (int p = 0; p < 8; ++p) {
        const int r = p * 16 + srow;
        *reinterpret_cast<ushort4*>(&Ws[0][r * PAD + scol * 4]) =
            make_ushort4(bfc(wr_[p][0]), bfc(wr_[p][1]), bfc(wr_[p][2]), bfc(wr_[p][3]));
    }
    __syncthreads();

    for (int k = 0; k < NKT; ++k) {
        const int cur = k & 1;

        // ---- cvt x(k) regs -> B-fragments (x(k) drained at last barrier) ----
        bf16x8 xf[2][2];   // [mt][ks]
        #pragma unroll
        for (int mt = 0; mt < 2; ++mt)
            #pragma unroll
            for (int ks = 0; ks < 2; ++ks)
                xf[mt][ks] = pack8(xr[mt*4 + ks*2 + 0], xr[mt*4 + ks*2 + 1]);

        // ---- issue x(k+1) + W(k+1): in flight across the MFMA phase ----
        if (k + 1 < NKT) {
            const int kt = (k + 1) * BK;
            #pragma unroll
            for (int ks = 0; ks < 2; ++ks)
                #pragma unroll
                for (int h = 0; h < 2; ++h) {
                    xr[0*4 + ks*2 + h] = *reinterpret_cast<const f32x4*>(xp0 + kt + ks*32 + h*4);
                    xr[1*4 + ks*2 + h] = *reinterpret_cast<const f32x4*>(xp1 + kt + ks*32 + h*4);
                }
            #pragma unroll
            for (int p = 0; p < 8; ++p) {
                const int r = p * 16 + srow;
                wr_[p] = *reinterpret_cast<const f32x4*>(&W[r * D_IN + kt + scol * 4]);
            }
        }

        // ---- compute: 16 ds_read_b128 (W frags) + 32 MFMA ----
        #pragma unroll
        for (int ci = 0; ci < 8; ++ci) {
            #pragma unroll
            for (int ks = 0; ks < 2; ++ks) {
                const bf16x8 a = *reinterpret_cast<const bf16x8*>(
                    &Ws[cur][(ci*16 + lr) * PAD + ks*32 + q*8]);
                acc[ci][0] = __builtin_amdgcn_mfma_f32_16x16x32_bf16(a, xf[0][ks], acc[ci][0], 0, 0, 0);
                acc[ci][1] = __builtin_amdgcn_mfma_f32_16x16x32_bf16(a, xf[1][ks], acc[ci][1], 0, 0, 0);
            }
        }

        // ---- stage W(k+1) into other buffer; ONE barrier per K-step ----
        if (k + 1 < NKT) {
            #pragma unroll
            for (int p = 0; p < 8; ++p) {
                const int r = p * 16 + srow;
                *reinterpret_cast<ushort4*>(&Ws[cur ^ 1][r * PAD + scol * 4]) =
                    make_ushort4(bfc(wr_[p][0]), bfc(wr_[p][1]), bfc(wr_[p][2]), bfc(wr_[p][3]));
            }
            __syncthreads();
        }
    }

    // ---- epilogue: D row = c-local (q*4+jj), col = m-local (lr) ----
    float* outb = out + (size_t)bidx * C_OUT * HW;
    #pragma unroll
    for (int ci = 0; ci < 8; ++ci) {
        #pragma unroll
        for (int jj = 0; jj < 4; ++jj) {
            const int c  = ci * 16 + q * 4 + jj;
            const float bv = bias[c];
            const size_t base = (size_t)c * HW + hw0 + wid * 32 + lr;
            outb[base]      = acc[ci][0][jj] + bv;
            outb[base + 16] = acc[ci][1][jj] + bv;
        }
    }
}

extern "C" void kernel_launch(void* const* d_in, const int* in_sizes, int n_in,
                              void* d_out, int out_size, void* d_ws, size_t ws_size,
                              hipStream_t stream) {
    const float* x    = (const float*)d_in[0];
    const float* W    = (const float*)d_in[1];
    const float* b    = (const float*)d_in[2];
    float* out        = (float*)d_out;
    const int M = 4 * HW;              // 65536 rows
    dim3 grid(M / BM);                 // 512 blocks, 2 per CU
    cwp_gemm<<<grid, 256, 0, stream>>>(x, W, b, out);
}

// Round 11
// 29.569 us; speedup vs baseline: 1.3132x; 1.3132x over previous
//
#include <hip/hip_runtime.h>
#include <hip/hip_bf16.h>

#define D_IN  512
#define C_OUT 128
#define HW    16384   // 128*128 per batch
#define BM    128
#define BK    64
#define PAD   72      // 144B row stride -> 2-way LDS aliasing on b128 reads (free, m136)
#define NKT   (D_IN / BK)   // 8 K-steps

typedef __attribute__((ext_vector_type(8))) short bf16x8;
typedef __attribute__((ext_vector_type(4))) float f32x4;

__device__ __forceinline__ ushort bf(float f) {
    // scalar cast -> compiler emits packed v_cvt_pk_bf16_f32 (RNE), per m240
    return __builtin_bit_cast(ushort, __float2bfloat16(f));
}

__global__ __launch_bounds__(256) void cwp_gemm(
    const float* __restrict__ x, const float* __restrict__ W,
    const float* __restrict__ bias, float* __restrict__ out)
{
    // double-buffered: 2 x (18.4 + 18.4) KB = 73.7 KB -> still 2 blocks/CU
    __shared__ ushort Ws[2][C_OUT * PAD];   // [c][k] bf16
    __shared__ ushort Xs[2][BM * PAD];      // [m][k] bf16

    const int t    = threadIdx.x;
    const int lane = t & 63;
    const int wid  = t >> 6;     // 0..3
    const int wr   = wid >> 1;   // c-half of block tile
    const int wc   = wid & 1;    // m-half of block tile
    const int q    = lane >> 4;  // 0..3
    const int lr   = lane & 15;

    const int m0   = blockIdx.x * BM;
    const int bidx = m0 / HW;
    const int hw0  = m0 % HW;

    f32x4 acc[4][4];
    #pragma unroll
    for (int i = 0; i < 4; ++i)
        #pragma unroll
        for (int j = 0; j < 4; ++j)
            acc[i][j] = (f32x4){0.f, 0.f, 0.f, 0.f};

    const int srow = t >> 4;  // 0..15: row-within-pass
    const int scol = t & 15;  // f32x4 column within BK

    f32x4 wv[8], xv[8];

    // ---- prologue: issue loads for tile 0 ----
    #pragma unroll
    for (int p = 0; p < 8; ++p) {
        const int r = p * 16 + srow;
        wv[p] = *reinterpret_cast<const f32x4*>(&W[r * D_IN + scol * 4]);
        xv[p] = *reinterpret_cast<const f32x4*>(&x[(size_t)(m0 + r) * D_IN + scol * 4]);
    }

    for (int k = 0; k < NKT; ++k) {
        const int cur = k & 1;

        // ---- cvt + LDS write tile k into buf[cur] ----
        // (first use of loads(k): implicit vmcnt wait here, hidden under
        //  compute(k-1) which ran since they were issued)
        // hazard: buf[cur]'s previous readers were compute(k-2), separated
        // by iteration k-1's barrier.
        #pragma unroll
        for (int p = 0; p < 8; ++p) {
            const int r = p * 16 + srow;
            *reinterpret_cast<ushort4*>(&Ws[cur][r * PAD + scol * 4]) =
                make_ushort4(bf(wv[p][0]), bf(wv[p][1]), bf(wv[p][2]), bf(wv[p][3]));
            *reinterpret_cast<ushort4*>(&Xs[cur][r * PAD + scol * 4]) =
                make_ushort4(bf(xv[p][0]), bf(xv[p][1]), bf(xv[p][2]), bf(xv[p][3]));
        }
        __syncthreads();  // the ONLY barrier per K-step: tile k visible

        // ---- issue loads(k+1) AFTER the barrier (so its vmcnt(0) drain
        //      can't touch them); they land during compute(k) ----
        if (k + 1 < NKT) {
            const int kt = (k + 1) * BK;
            #pragma unroll
            for (int p = 0; p < 8; ++p) {
                const int r = p * 16 + srow;
                wv[p] = *reinterpret_cast<const f32x4*>(&W[r * D_IN + kt + scol * 4]);
                xv[p] = *reinterpret_cast<const f32x4*>(&x[(size_t)(m0 + r) * D_IN + kt + scol * 4]);
            }
        }

        // ---- compute tile k: 2 k-subs x 16 MFMA per wave ----
        #pragma unroll
        for (int ks = 0; ks < 2; ++ks) {
            bf16x8 af[4], bfv[4];
            #pragma unroll
            for (int i = 0; i < 4; ++i) {
                af[i]  = *reinterpret_cast<const bf16x8*>(&Ws[cur][(wr*64 + i*16 + lr) * PAD + ks*32 + q*8]);
                bfv[i] = *reinterpret_cast<const bf16x8*>(&Xs[cur][(wc*64 + i*16 + lr) * PAD + ks*32 + q*8]);
            }
            #pragma unroll
            for (int i = 0; i < 4; ++i)
                #pragma unroll
                for (int j = 0; j < 4; ++j)
                    acc[i][j] = __builtin_amdgcn_mfma_f32_16x16x32_bf16(af[i], bfv[j], acc[i][j], 0, 0, 0);
        }
    }

    // ---- epilogue: D[row=c-local][col=m-local]; row=(lane>>4)*4+jj, col=lane&15 ----
    float bv[4][4];
    #pragma unroll
    for (int i = 0; i < 4; ++i)
        #pragma unroll
        for (int jj = 0; jj < 4; ++jj)
            bv[i][jj] = bias[wr*64 + i*16 + q*4 + jj];

    float* outb = out + (size_t)bidx * C_OUT * HW;
    #pragma unroll
    for (int i = 0; i < 4; ++i) {
        const int c0 = wr*64 + i*16 + q*4;
        #pragma unroll
        for (int j = 0; j < 4; ++j) {
            const int m = hw0 + wc*64 + j*16 + lr;
            #pragma unroll
            for (int jj = 0; jj < 4; ++jj)
                outb[(size_t)(c0 + jj) * HW + m] = acc[i][j][jj] + bv[i][jj];
        }
    }
}

extern "C" void kernel_launch(void* const* d_in, const int* in_sizes, int n_in,
                              void* d_out, int out_size, void* d_ws, size_t ws_size,
                              hipStream_t stream) {
    const float* x    = (const float*)d_in[0];
    const float* W    = (const float*)d_in[1];
    const float* b    = (const float*)d_in[2];
    float* out        = (float*)d_out;
    const int M = 4 * HW;              // 65536 rows
    dim3 grid(M / BM);                 // 512 blocks, 2 per CU
    cwp_gemm<<<grid, 256, 0, stream>>>(x, W, b, out);
}